// Round 17
// baseline (28036.932 us; speedup 1.0000x reference)
//
#include <hip/hip_runtime.h>
#include <hip/hip_bf16.h>

// Problem constants
#define HH 1024
#define BB 128
#define TT 512
#define NWG 128      // 4 row-groups (mg = wg>>5) x 32 N-slices (ng = wg&31)
#define NTH 512      // 8 waves: 2 M-tiles (wm) x 4 K-quarters (kq); each wave does BOTH wn tiles
#define NP 32

typedef float        f32x4 __attribute__((ext_vector_type(4)));
typedef short        s16x8 __attribute__((ext_vector_type(8)));

__device__ __forceinline__ unsigned short bf16b(float f) {
    union { __hip_bfloat16 h; unsigned short u; } cv;
    cv.h = __float2bfloat16(f);
    return cv.u;
}

__device__ __forceinline__ float gelu_exact(float x) {
    return 0.5f * x * (1.0f + erff(x * 0.70710678118654752440f));
}

// --- device-coherent (system-scope) accesses: cross-WG producer/consumer.
__device__ __forceinline__ void sc_load_b16x8(s16x8& v, const unsigned short* p) {
    asm volatile("global_load_dwordx4 %0, %1, off sc0 sc1" : "=v"(v) : "v"(p));
}
__device__ __forceinline__ void sc_load_u32(unsigned& v, const unsigned* p) {
    asm volatile("global_load_dword %0, %1, off sc0 sc1" : "=v"(v) : "v"(p));
}
__device__ __forceinline__ void sc_store_b16(unsigned short* p, unsigned int v) {
    asm volatile("global_store_short %0, %1, off sc0 sc1" :: "v"(p), "v"(v) : "memory");
}
__device__ __forceinline__ void sc_store_u32(unsigned* p, unsigned int v) {
    asm volatile("global_store_dword %0, %1, off sc0 sc1" :: "v"(p), "v"(v) : "memory");
}
// --- plain cached load (weights -> L2-resident under mod-8 mapping).
__device__ __forceinline__ void pl_load_b16x8(s16x8& v, const unsigned short* p) {
    asm volatile("global_load_dwordx4 %0, %1, off" : "=v"(v) : "v"(p));
}
// --- non-temporal store for streaming Out writes (no L2 pollution).
__device__ __forceinline__ void nt_store_f32(float* p, float v) {
    asm volatile("global_store_dword %0, %1, off nt" :: "v"(p), "v"(v) : "memory");
}
__device__ __forceinline__ void vm_wait0() {
    asm volatile("s_waitcnt vmcnt(0)" ::: "memory");
    __builtin_amdgcn_sched_barrier(0);   // rule #18
}

// ---------------------------------------------------------------------------
// Pack fp32 weight W[K][N] (row-major) into MFMA B-fragment layout, bf16.
// ---------------------------------------------------------------------------
__global__ __launch_bounds__(256) void pack_w_kernel(const float* __restrict__ W,
                                                     unsigned short* __restrict__ P,
                                                     int K, int N) {
    int tid = blockIdx.x * 256 + threadIdx.x;
    int KT = K >> 5;
    int total = (N >> 4) * KT * 64;
    if (tid >= total) return;
    int lane  = tid & 63;
    int ktile = (tid >> 6) % KT;
    int ntile = (tid >> 6) / KT;
    int k0 = ktile * 32 + (lane >> 4) * 8;
    int n  = ntile * 16 + (lane & 15);
    unsigned short tmp[8];
#pragma unroll
    for (int j = 0; j < 8; ++j)
        tmp[j] = bf16b(W[(size_t)(k0 + j) * N + n]);
    *reinterpret_cast<s16x8*>(P + (size_t)tid * 8) = *reinterpret_cast<const s16x8*>(tmp);
}

// ---------------------------------------------------------------------------
// Pack fp32 X into bf16 (identical rounding to the on-the-fly path).
// ---------------------------------------------------------------------------
__global__ __launch_bounds__(256) void pack_x_kernel(const float* __restrict__ X,
                                                     unsigned short* __restrict__ Xb,
                                                     int n8) {
    int i = blockIdx.x * 256 + threadIdx.x;
    if (i >= n8) return;
    f32x4 lo = *reinterpret_cast<const f32x4*>(X + (size_t)i * 8);
    f32x4 hi = *reinterpret_cast<const f32x4*>(X + (size_t)i * 8 + 4);
    unsigned short tmp[8];
#pragma unroll
    for (int j = 0; j < 4; ++j) {
        tmp[j]     = bf16b(lo[j]);
        tmp[j + 4] = bf16b(hi[j]);
    }
    *reinterpret_cast<s16x8*>(Xb + (size_t)i * 8) = *reinterpret_cast<const s16x8*>(tmp);
}

// ---------------------------------------------------------------------------
// Per-GROUP flag barrier (r16-proven): 32 WGs of one row-group; dense slots.
// ---------------------------------------------------------------------------
__device__ __forceinline__ void gbar_arrive(unsigned* gs, int ng, unsigned rnd) {
    asm volatile("s_waitcnt vmcnt(0)" ::: "memory");  // drain my sc/nt stores
    __syncthreads();                                   // all 8 waves drained
    if (threadIdx.x == 0)
        sc_store_u32(gs + ng, rnd);
}
__device__ __forceinline__ void gbar_wait(unsigned* gs, unsigned rnd) {
    if (threadIdx.x < 64) {
        const unsigned* p = gs + (threadIdx.x & 31);
        bool done;
        do {
            unsigned v;
            sc_load_u32(v, p);
            asm volatile("s_waitcnt vmcnt(0)" ::: "memory");
            done = __all(v >= rnd);
        } while (!done);
    }
    __syncthreads();
    __builtin_amdgcn_sched_barrier(0);
}

// ---------------------------------------------------------------------------
// x-quarter (16 kt) dual-wn loop: plain cached loads, pure C++ (compiler
// schedules). Static input -> runs BEFORE barrier waits.
// ---------------------------------------------------------------------------
__device__ __forceinline__ void kloop_xb2(const unsigned short* xq,
                                          const unsigned short* b0p,
                                          const unsigned short* b1p,
                                          f32x4& A0, f32x4& A1) {
#pragma unroll 4
    for (int kt = 0; kt < 16; ++kt) {
        s16x8 a  = *reinterpret_cast<const s16x8*>(xq + kt * 32);
        s16x8 b0 = *reinterpret_cast<const s16x8*>(b0p + (size_t)kt * 512);
        s16x8 b1 = *reinterpret_cast<const s16x8*>(b1p + (size_t)kt * 512);
        A0 = __builtin_amdgcn_mfma_f32_16x16x32_bf16(a, b0, A0, 0, 0, 0);
        A1 = __builtin_amdgcn_mfma_f32_16x16x32_bf16(a, b1, A1, 0, 0, 0);
    }
}

// ---------------------------------------------------------------------------
// state-quarter (16 kt) dual-wn trickle loop: 2 blocks of 8 kt; per block
// 8 sc A + 16 plain (L2-hit) B = 24 outstanding max, vmcnt(0) drain -> 2 RT.
// ---------------------------------------------------------------------------
__device__ __forceinline__ void kloop_st2(const unsigned short* Abase,
                                          const unsigned short* b0p,
                                          const unsigned short* b1p,
                                          f32x4& A0, f32x4& A1) {
    for (int blk = 0; blk < 2; ++blk) {
        int kb = blk * 8;
        s16x8 a[8], b0[8], b1[8];
#pragma unroll
        for (int j = 0; j < 8; ++j)
            sc_load_b16x8(a[j], Abase + (size_t)(kb + j) * 32);
#pragma unroll
        for (int j = 0; j < 8; ++j)
            pl_load_b16x8(b0[j], b0p + (size_t)(kb + j) * 512);
#pragma unroll
        for (int j = 0; j < 8; ++j)
            pl_load_b16x8(b1[j], b1p + (size_t)(kb + j) * 512);
        vm_wait0();
#pragma unroll
        for (int j = 0; j < 8; ++j) {
            A0 = __builtin_amdgcn_mfma_f32_16x16x32_bf16(a[j], b0[j], A0, 0, 0, 0);
            A1 = __builtin_amdgcn_mfma_f32_16x16x32_bf16(a[j], b1[j], A1, 0, 0, 0);
        }
    }
}

// ---------------------------------------------------------------------------
// G2/G4 quarter (8 kt) dual-wn: 8 sc A upfront (1 RT), B from LDS weights.
// ---------------------------------------------------------------------------
__device__ __forceinline__ void kloop_ds8(const unsigned short* Abase,
                                          const char* w0, const char* w1, int kq,
                                          f32x4& A0, f32x4& A1) {
    s16x8 a[8];
#pragma unroll
    for (int j = 0; j < 8; ++j)
        sc_load_b16x8(a[j], Abase + (size_t)j * 32);
    vm_wait0();
#pragma unroll
    for (int j = 0; j < 8; ++j) {
        s16x8 b0 = *reinterpret_cast<const s16x8*>(w0 + (size_t)(kq * 8 + j) * 1024);
        s16x8 b1 = *reinterpret_cast<const s16x8*>(w1 + (size_t)(kq * 8 + j) * 1024);
        A0 = __builtin_amdgcn_mfma_f32_16x16x32_bf16(a[j], b0, A0, 0, 0, 0);
        A1 = __builtin_amdgcn_mfma_f32_16x16x32_bf16(a[j], b1, A1, 0, 0, 0);
    }
}

// ---------------------------------------------------------------------------
// Persistent kernel (r16 skeleton). Waves: wm = w>>2 (2 M-tiles of 16),
// kq = w&3 (4 K-quarters); each wave computes BOTH wn tiles of its M-tile
// (A-fragments shared -> sc loads halved). kq 1..3 park partials in LDS;
// kq 0 reduces + runs the epilogue. x-work (static input) is hoisted into
// the preceding barrier wait: G1-x in G4(t-1)-pre / prologue, G3-x in
// G2-pre, G4's fp32 xv in G4-pre. Barrier, mapping, LDS-pinned G2/G4
// weights, trickle discipline: all r16-proven.
// ---------------------------------------------------------------------------
__global__ __launch_bounds__(512, 1) void persist_kernel(
    const float* __restrict__ X, const unsigned short* __restrict__ Xb,
    const unsigned short* __restrict__ p_a1, const float* __restrict__ ab1,
    const unsigned short* __restrict__ p_a2, const float* __restrict__ ab2,
    const unsigned short* __restrict__ p_g1, const float* __restrict__ gb1,
    const unsigned short* __restrict__ p_g2, const float* __restrict__ gb2,
    float* __restrict__ Out,
    unsigned short* state, unsigned short* h1, unsigned short* albf,
    unsigned short* h2,
    unsigned* slots)
{
    __shared__ __align__(16) char wlds[131072];   // 128 KB G2/G4 weight frags
    __shared__ f32x4 red[2][3][2][64];            // 12 KB 4-way K reduction

    const int wg    = blockIdx.x;
    const int ng    = wg & (NP - 1);  // mod-8 XCD-friendly N-slice
    const int mg    = wg >> 5;        // row-group
    const int tid   = threadIdx.x;
    const int lane  = tid & 63;
    const int w     = tid >> 6;       // 0..7
    const int wm    = w >> 2;         // 0..1 M-tile
    const int kq    = w & 3;          // 0..3 K-quarter
    const int r     = lane & 15;
    const int q     = lane >> 4;

    const int mrow = mg * 32 + wm * 16;
    const int c0   = ng * 32 + r;          // wn=0 column
    const int c1   = c0 + 16;              // wn=1 column
    const int nt0  = ng * 2, nt1 = nt0 + 1;

    unsigned* gs = slots + mg * 64;        // group's dense 32-slot block

    const size_t arow_off = (size_t)(mrow + r) * HH + q * 8;
    const unsigned short* xrowb = Xb + (size_t)(mrow + r) * (TT * HH) + q * 8;

    const unsigned short* a1_0 = p_a1 + ((size_t)nt0 * 64) * 512 + (size_t)lane * 8;
    const unsigned short* a1_1 = p_a1 + ((size_t)nt1 * 64) * 512 + (size_t)lane * 8;
    const unsigned short* g1_0 = p_g1 + ((size_t)nt0 * 64) * 512 + (size_t)lane * 8;
    const unsigned short* g1_1 = p_g1 + ((size_t)nt1 * 64) * 512 + (size_t)lane * 8;

    const float bA1[2] = {ab1[c0], ab1[c1]};
    const float bA2[2] = {ab2[c0], ab2[c1]};
    const float bG1[2] = {gb1[c0], gb1[c1]};
    const float bG2[2] = {gb2[c0], gb2[c1]};

    // ---- prologue: pin this WG's G2/G4 weight fragments in LDS -----------
    for (int idx = tid; idx < 8192; idx += NTH) {
        int g   = idx >> 12;
        int rem = idx & 4095;
        int ntl = rem >> 11;
        int kt  = (rem >> 6) & 31;
        int ln  = rem & 63;
        const unsigned short* src = (g ? p_g2 : p_a2)
            + ((size_t)((ng * 2 + ntl) * 32 + kt) * 64 + ln) * 8;
        *reinterpret_cast<s16x8*>(wlds + (size_t)idx * 16) =
            *reinterpret_cast<const s16x8*>(src);
    }
    __syncthreads();

    // LDS weight bases (per ntl; quarter offset applied inside kloop_ds8)
    const char* wA2_0 = wlds + (size_t)lane * 16;
    const char* wA2_1 = wA2_0 + 32768;
    const char* wG2_0 = wA2_0 + 65536;
    const char* wG2_1 = wA2_0 + 98304;

    float al0[4], al1[4];                 // fp32 'aligned' tiles (kq 0 only)
    f32x4 xacc0 = {}, xacc1 = {};         // carried x-partials (kq < 2)

    // ---- prologue: G1(t=0) x-partials --------------------------------------
    if (kq < 2)
        kloop_xb2(xrowb + (size_t)kq * 512,
                  a1_0 + (size_t)kq * 16 * 512, a1_1 + (size_t)kq * 16 * 512,
                  xacc0, xacc1);

    for (int t = 0; t < TT; ++t) {
        const unsigned short* xtb = xrowb + (size_t)t * HH;
        const unsigned rb = 4u * (unsigned)t;

        // ------- G1: h1 = gelu(concat(x_t, state) @ aw1 + ab1), K=2048 -----
        {
            f32x4 A0 = xacc0, A1 = xacc1;           // kq<2: carried x-partials
            gbar_wait(gs, rb);                      // state ready (G4 t-1)
            if (kq >= 2) {
                A0 = (f32x4){}; A1 = (f32x4){};
                int s = kq - 2;
                kloop_st2(state + arow_off + (size_t)s * 512,
                          a1_0 + (size_t)(32 + s * 16) * 512,
                          a1_1 + (size_t)(32 + s * 16) * 512, A0, A1);
            }
            if (kq > 0) { red[wm][kq - 1][0][lane] = A0; red[wm][kq - 1][1][lane] = A1; }
            __syncthreads();
            if (kq == 0) {
                A0 += red[wm][0][0][lane] + red[wm][1][0][lane] + red[wm][2][0][lane];
                A1 += red[wm][0][1][lane] + red[wm][1][1][lane] + red[wm][2][1][lane];
#pragma unroll
                for (int j = 0; j < 4; ++j) {
                    size_t rowo = (size_t)(mrow + q * 4 + j) * HH;
                    sc_store_b16(h1 + rowo + c0, bf16b(gelu_exact(A0[j] + bA1[0])));
                    sc_store_b16(h1 + rowo + c1, bf16b(gelu_exact(A1[j] + bA1[1])));
                }
            }
        }
        gbar_arrive(gs, ng, rb + 1);

        // ------- G2: aligned = h1 @ aw2 + ab2, K=1024 (B from LDS) ---------
        {
            // pre-wait: G3's x-partials (static input) into carried regs
            if (kq < 2) {
                xacc0 = (f32x4){}; xacc1 = (f32x4){};
                kloop_xb2(xtb + (size_t)kq * 512,
                          g1_0 + (size_t)kq * 16 * 512, g1_1 + (size_t)kq * 16 * 512,
                          xacc0, xacc1);
            }
            gbar_wait(gs, rb + 1);
            f32x4 A0 = {}, A1 = {};
            kloop_ds8(h1 + arow_off + (size_t)kq * 256, wA2_0, wA2_1, kq, A0, A1);
            if (kq > 0) { red[wm][kq - 1][0][lane] = A0; red[wm][kq - 1][1][lane] = A1; }
            __syncthreads();
            if (kq == 0) {
                A0 += red[wm][0][0][lane] + red[wm][1][0][lane] + red[wm][2][0][lane];
                A1 += red[wm][0][1][lane] + red[wm][1][1][lane] + red[wm][2][1][lane];
#pragma unroll
                for (int j = 0; j < 4; ++j) {
                    size_t rowo = (size_t)(mrow + q * 4 + j) * HH;
                    float v0 = A0[j] + bA2[0], v1 = A1[j] + bA2[1];
                    al0[j] = v0; al1[j] = v1;
                    sc_store_b16(albf + rowo + c0, bf16b(v0));
                    sc_store_b16(albf + rowo + c1, bf16b(v1));
                }
            }
        }
        gbar_arrive(gs, ng, rb + 2);

        // ------- G3: h2 = gelu(concat(x_t, aligned) @ gw1 + gb1), K=2048 ---
        {
            f32x4 A0 = xacc0, A1 = xacc1;           // kq<2: G2-pre partials
            gbar_wait(gs, rb + 2);                  // albf ready
            if (kq >= 2) {
                A0 = (f32x4){}; A1 = (f32x4){};
                int s = kq - 2;
                kloop_st2(albf + arow_off + (size_t)s * 512,
                          g1_0 + (size_t)(32 + s * 16) * 512,
                          g1_1 + (size_t)(32 + s * 16) * 512, A0, A1);
            }
            if (kq > 0) { red[wm][kq - 1][0][lane] = A0; red[wm][kq - 1][1][lane] = A1; }
            __syncthreads();
            if (kq == 0) {
                A0 += red[wm][0][0][lane] + red[wm][1][0][lane] + red[wm][2][0][lane];
                A1 += red[wm][0][1][lane] + red[wm][1][1][lane] + red[wm][2][1][lane];
#pragma unroll
                for (int j = 0; j < 4; ++j) {
                    size_t rowo = (size_t)(mrow + q * 4 + j) * HH;
                    sc_store_b16(h2 + rowo + c0, bf16b(gelu_exact(A0[j] + bG1[0])));
                    sc_store_b16(h2 + rowo + c1, bf16b(gelu_exact(A1[j] + bG1[1])));
                }
            }
        }
        gbar_arrive(gs, ng, rb + 3);

        // ------- G4: gate = sigmoid(h2 @ gw2 + gb2); blend (B from LDS) ----
        {
            // pre-wait: next step's G1 x-partials + this step's fp32 xv
            if (kq < 2 && t + 1 < TT) {
                xacc0 = (f32x4){}; xacc1 = (f32x4){};
                kloop_xb2(xtb + HH + (size_t)kq * 512,
                          a1_0 + (size_t)kq * 16 * 512, a1_1 + (size_t)kq * 16 * 512,
                          xacc0, xacc1);
            }
            float xv0[4], xv1[4];
            if (kq == 0) {
#pragma unroll
                for (int j = 0; j < 4; ++j) {
                    size_t xo = (size_t)(mrow + q * 4 + j) * (TT * HH) + (size_t)t * HH;
                    xv0[j] = X[xo + c0];
                    xv1[j] = X[xo + c1];
                }
            }
            gbar_wait(gs, rb + 3);
            f32x4 A0 = {}, A1 = {};
            kloop_ds8(h2 + arow_off + (size_t)kq * 256, wG2_0, wG2_1, kq, A0, A1);
            if (kq > 0) { red[wm][kq - 1][0][lane] = A0; red[wm][kq - 1][1][lane] = A1; }
            __syncthreads();
            if (kq == 0) {
                A0 += red[wm][0][0][lane] + red[wm][1][0][lane] + red[wm][2][0][lane];
                A1 += red[wm][0][1][lane] + red[wm][1][1][lane] + red[wm][2][1][lane];
#pragma unroll
                for (int j = 0; j < 4; ++j) {
                    int row = mrow + q * 4 + j;
                    size_t xo = (size_t)row * (TT * HH) + (size_t)t * HH;
                    size_t so = (size_t)row * HH;
                    float g0 = 1.0f / (1.0f + expf(-(A0[j] + bG2[0])));
                    float g1 = 1.0f / (1.0f + expf(-(A1[j] + bG2[1])));
                    float o0 = g0 * al0[j] + (1.0f - g0) * xv0[j];
                    float o1 = g1 * al1[j] + (1.0f - g1) * xv1[j];
                    nt_store_f32(Out + xo + c0, o0);
                    nt_store_f32(Out + xo + c1, o1);
                    sc_store_b16(state + so + c0, bf16b(o0));
                    sc_store_b16(state + so + c1, bf16b(o1));
                }
            }
        }
        gbar_arrive(gs, ng, rb + 4);
    }
}

extern "C" void kernel_launch(void* const* d_in, const int* in_sizes, int n_in,
                              void* d_out, int out_size, void* d_ws, size_t ws_size,
                              hipStream_t stream) {
    (void)in_sizes; (void)n_in; (void)out_size; (void)ws_size;
    const float* X   = (const float*)d_in[0];
    const float* aw1 = (const float*)d_in[1];
    const float* ab1 = (const float*)d_in[2];
    const float* aw2 = (const float*)d_in[3];
    const float* ab2 = (const float*)d_in[4];
    const float* gw1 = (const float*)d_in[5];
    const float* gb1 = (const float*)d_in[6];
    const float* gw2 = (const float*)d_in[7];
    const float* gb2 = (const float*)d_in[8];
    float* Out = (float*)d_out;

    char* ws = (char*)d_ws;
    unsigned short* p_a1 = (unsigned short*)(ws);                 // 4 MB
    unsigned short* p_g1 = (unsigned short*)(ws + (4u  << 20));   // 4 MB
    unsigned short* p_a2 = (unsigned short*)(ws + (8u  << 20));   // 2 MB
    unsigned short* p_g2 = (unsigned short*)(ws + (10u << 20));   // 2 MB
    char* ctrl = ws + (12u << 20);
    unsigned* slots = (unsigned*)ctrl;                            // 4 grp x 64 u32
    unsigned short* state = (unsigned short*)(ctrl + 4096);       // 256 KB
    unsigned short* h1    = state + (size_t)BB * HH;              // 256 KB
    unsigned short* albf  = h1    + (size_t)BB * HH;              // 256 KB
    unsigned short* h2    = albf  + (size_t)BB * HH;              // 256 KB
    unsigned short* xbf   = (unsigned short*)(ws + (16u << 20));  // 128 MB

    pack_w_kernel<<<(64 * 64 * 64 + 255) / 256, 256, 0, stream>>>(aw1, p_a1, 2048, 1024);
    pack_w_kernel<<<(64 * 64 * 64 + 255) / 256, 256, 0, stream>>>(gw1, p_g1, 2048, 1024);
    pack_w_kernel<<<(64 * 32 * 64 + 255) / 256, 256, 0, stream>>>(aw2, p_a2, 1024, 1024);
    pack_w_kernel<<<(64 * 32 * 64 + 255) / 256, 256, 0, stream>>>(gw2, p_g2, 1024, 1024);
    {
        int n8 = BB * TT * HH / 8;
        pack_x_kernel<<<(n8 + 255) / 256, 256, 0, stream>>>(X, xbf, n8);
    }
    // Zero barrier slots + recurrent state every call (graph-replay safe).
    hipMemsetAsync(ctrl, 0, 4096 + (size_t)BB * HH * sizeof(unsigned short), stream);

    persist_kernel<<<NWG, NTH, 0, stream>>>(X, xbf, p_a1, ab1, p_a2, ab2,
                                            p_g1, gb1, p_g2, gb2,
                                            Out, state, h1, albf, h2, slots);
}

// Round 18
// 12679.610 us; speedup vs baseline: 2.2112x; 2.2112x over previous
//
#include <hip/hip_runtime.h>
#include <hip/hip_bf16.h>

// Problem constants
#define HH 1024
#define BB 128
#define TT 512
#define NWG 256      // 8 row-groups (mg = wg>>5, 16 rows) x 32 N-slices (ng = wg&31)
#define NTH 512      // 8 waves: 2 ntiles (wn = w>>2) x 4 K-quarters (kq = w&3)
#define NP 32

typedef float        f32x4 __attribute__((ext_vector_type(4)));
typedef short        s16x8 __attribute__((ext_vector_type(8)));

__device__ __forceinline__ unsigned short bf16b(float f) {
    union { __hip_bfloat16 h; unsigned short u; } cv;
    cv.h = __float2bfloat16(f);
    return cv.u;
}

__device__ __forceinline__ float gelu_exact(float x) {
    return 0.5f * x * (1.0f + erff(x * 0.70710678118654752440f));
}

// --- device-coherent (system-scope) accesses: cross-WG producer/consumer.
__device__ __forceinline__ void sc_load_b16x8(s16x8& v, const unsigned short* p) {
    asm volatile("global_load_dwordx4 %0, %1, off sc0 sc1" : "=v"(v) : "v"(p));
}
__device__ __forceinline__ void sc_load_u32(unsigned& v, const unsigned* p) {
    asm volatile("global_load_dword %0, %1, off sc0 sc1" : "=v"(v) : "v"(p));
}
__device__ __forceinline__ void sc_store_b16(unsigned short* p, unsigned int v) {
    asm volatile("global_store_short %0, %1, off sc0 sc1" :: "v"(p), "v"(v) : "memory");
}
__device__ __forceinline__ void sc_store_u32(unsigned* p, unsigned int v) {
    asm volatile("global_store_dword %0, %1, off sc0 sc1" :: "v"(p), "v"(v) : "memory");
}
// --- plain cached load (weights -> L2-resident under mod-8 mapping).
__device__ __forceinline__ void pl_load_b16x8(s16x8& v, const unsigned short* p) {
    asm volatile("global_load_dwordx4 %0, %1, off" : "=v"(v) : "v"(p));
}
// --- non-temporal store for streaming Out writes (no L2 pollution).
__device__ __forceinline__ void nt_store_f32(float* p, float v) {
    asm volatile("global_store_dword %0, %1, off nt" :: "v"(p), "v"(v) : "memory");
}
__device__ __forceinline__ void vm_wait0() {
    asm volatile("s_waitcnt vmcnt(0)" ::: "memory");
    __builtin_amdgcn_sched_barrier(0);   // rule #18
}

// ---------------------------------------------------------------------------
// Pack fp32 weight W[K][N] (row-major) into MFMA B-fragment layout, bf16.
// ---------------------------------------------------------------------------
__global__ __launch_bounds__(256) void pack_w_kernel(const float* __restrict__ W,
                                                     unsigned short* __restrict__ P,
                                                     int K, int N) {
    int tid = blockIdx.x * 256 + threadIdx.x;
    int KT = K >> 5;
    int total = (N >> 4) * KT * 64;
    if (tid >= total) return;
    int lane  = tid & 63;
    int ktile = (tid >> 6) % KT;
    int ntile = (tid >> 6) / KT;
    int k0 = ktile * 32 + (lane >> 4) * 8;
    int n  = ntile * 16 + (lane & 15);
    unsigned short tmp[8];
#pragma unroll
    for (int j = 0; j < 8; ++j)
        tmp[j] = bf16b(W[(size_t)(k0 + j) * N + n]);
    *reinterpret_cast<s16x8*>(P + (size_t)tid * 8) = *reinterpret_cast<const s16x8*>(tmp);
}

// ---------------------------------------------------------------------------
// Pack fp32 X into bf16 (identical rounding to the on-the-fly path).
// ---------------------------------------------------------------------------
__global__ __launch_bounds__(256) void pack_x_kernel(const float* __restrict__ X,
                                                     unsigned short* __restrict__ Xb,
                                                     int n8) {
    int i = blockIdx.x * 256 + threadIdx.x;
    if (i >= n8) return;
    f32x4 lo = *reinterpret_cast<const f32x4*>(X + (size_t)i * 8);
    f32x4 hi = *reinterpret_cast<const f32x4*>(X + (size_t)i * 8 + 4);
    unsigned short tmp[8];
#pragma unroll
    for (int j = 0; j < 4; ++j) {
        tmp[j]     = bf16b(lo[j]);
        tmp[j + 4] = bf16b(hi[j]);
    }
    *reinterpret_cast<s16x8*>(Xb + (size_t)i * 8) = *reinterpret_cast<const s16x8*>(tmp);
}

// ---------------------------------------------------------------------------
// Per-GROUP flag barrier (r16-proven mechanism): 32 WGs of one row-group;
// dense 32-u32 slot block per group. Wave 0 polls, then block sync.
// ---------------------------------------------------------------------------
__device__ __forceinline__ void gbar_arrive(unsigned* gs, int ng, unsigned rnd) {
    asm volatile("s_waitcnt vmcnt(0)" ::: "memory");  // drain my sc/nt stores
    __syncthreads();                                   // all 8 waves drained
    if (threadIdx.x == 0)
        sc_store_u32(gs + ng, rnd);
}
__device__ __forceinline__ void gbar_wait(unsigned* gs, unsigned rnd) {
    if (threadIdx.x < 64) {
        const unsigned* p = gs + (threadIdx.x & 31);
        bool done;
        do {
            unsigned v;
            sc_load_u32(v, p);
            asm volatile("s_waitcnt vmcnt(0)" ::: "memory");
            done = __all(v >= rnd);
        } while (!done);
    }
    __syncthreads();
    __builtin_amdgcn_sched_barrier(0);
}

// ---------------------------------------------------------------------------
// x-eighth (8 kt) loop: plain cached loads, pure C++ (compiler schedules).
// Static input -> runs BEFORE the barrier wait.
// ---------------------------------------------------------------------------
__device__ __forceinline__ f32x4 kloop_x8(const unsigned short* xq,
                                          const unsigned short* bp) {
    f32x4 acc = {};
#pragma unroll
    for (int kt = 0; kt < 8; ++kt) {
        s16x8 a = *reinterpret_cast<const s16x8*>(xq + kt * 32);
        s16x8 b = *reinterpret_cast<const s16x8*>(bp + (size_t)kt * 512);
        acc = __builtin_amdgcn_mfma_f32_16x16x32_bf16(a, b, acc, 0, 0, 0);
    }
    return acc;
}

// ---------------------------------------------------------------------------
// 8-kt activation batch: 8 sc A + 8 plain B = 16 outstanding (the r13/r16
// PROVEN shape), ONE vmcnt(0) drain -> one exposed round-trip.
// ---------------------------------------------------------------------------
__device__ __forceinline__ f32x4 kloop_sc8(const unsigned short* Abase,
                                           const unsigned short* bp, f32x4 acc) {
    s16x8 a[8], b[8];
#pragma unroll
    for (int j = 0; j < 8; ++j)
        sc_load_b16x8(a[j], Abase + (size_t)j * 32);
#pragma unroll
    for (int j = 0; j < 8; ++j)
        pl_load_b16x8(b[j], bp + (size_t)j * 512);
    vm_wait0();
#pragma unroll
    for (int j = 0; j < 8; ++j)
        acc = __builtin_amdgcn_mfma_f32_16x16x32_bf16(a[j], b[j], acc, 0, 0, 0);
    return acc;
}

// ---------------------------------------------------------------------------
// 8-kt batch vs LDS-pinned weights: 8 sc A (one drain), B from LDS.
// wl pre-offset to this wave's (gemm, ntile, kq, lane).
// ---------------------------------------------------------------------------
__device__ __forceinline__ f32x4 kloop_ds8(const unsigned short* Abase,
                                           const char* wl) {
    f32x4 acc = {};
    s16x8 a[8];
#pragma unroll
    for (int j = 0; j < 8; ++j)
        sc_load_b16x8(a[j], Abase + (size_t)j * 32);
    vm_wait0();
#pragma unroll
    for (int j = 0; j < 8; ++j) {
        s16x8 b = *reinterpret_cast<const s16x8*>(wl + (size_t)j * 1024);
        acc = __builtin_amdgcn_mfma_f32_16x16x32_bf16(a[j], b, acc, 0, 0, 0);
    }
    return acc;
}

// ---------------------------------------------------------------------------
// Persistent kernel: 256 WGs = 8 row-groups (16 rows) x 32 col-slices.
// Per WG: 16 rows x 32 cols; 8 waves = 2 ntiles (wn) x 4 K-quarters (kq).
// Every post-wait kloop is a single 8sc+8plain batch (1 MALL round-trip).
// kq 1..3 park partials in LDS; kq 0 reduces + runs the epilogue.
// Load shapes identical to r16 (16-outstanding trickle); LDS-pinned G2/G4
// weights (128 KB); mod-8 ng mapping (G1/G3 weights 1 MB/XCD, L2-resident);
// X bf16-prepacked, x-eighth hoisted pre-wait. Activations sc0sc1; Out nt.
// ---------------------------------------------------------------------------
__global__ __launch_bounds__(512, 1) void persist_kernel(
    const float* __restrict__ X, const unsigned short* __restrict__ Xb,
    const unsigned short* __restrict__ p_a1, const float* __restrict__ ab1,
    const unsigned short* __restrict__ p_a2, const float* __restrict__ ab2,
    const unsigned short* __restrict__ p_g1, const float* __restrict__ gb1,
    const unsigned short* __restrict__ p_g2, const float* __restrict__ gb2,
    float* __restrict__ Out,
    unsigned short* state, unsigned short* h1, unsigned short* albf,
    unsigned short* h2,
    unsigned* slots)
{
    __shared__ __align__(16) char wlds[131072];   // 128 KB G2/G4 weight frags
    __shared__ f32x4 red[2][3][64];               // 6 KB 4-way K reduction

    const int wg   = blockIdx.x;
    const int ng   = wg & (NP - 1);   // mod-8 XCD-friendly N-slice
    const int mg   = wg >> 5;         // row-group (16 rows)
    const int tid  = threadIdx.x;
    const int lane = tid & 63;
    const int w    = tid >> 6;        // 0..7
    const int wn   = w >> 2;          // 0..1 ntile
    const int kq   = w & 3;           // 0..3 K-quarter
    const int r    = lane & 15;
    const int q    = lane >> 4;

    const int mrow  = mg * 16;                    // group's 16 rows
    const int ncol  = ng * 32 + wn * 16;          // wave's ntile base
    const int ntile = ncol >> 4;                  // = ng*2 + wn
    const int c0    = ncol + r;

    unsigned* gs = slots + mg * 64;               // group's dense 32-slot block

    const size_t arow_off = (size_t)(mrow + r) * HH + q * 8;
    const unsigned short* xrowb = Xb + (size_t)(mrow + r) * (TT * HH) + q * 8;

    const unsigned short* a1f = p_a1 + ((size_t)ntile * 64) * 512 + (size_t)lane * 8;
    const unsigned short* g1f = p_g1 + ((size_t)ntile * 64) * 512 + (size_t)lane * 8;

    const float bA1 = ab1[c0], bA2 = ab2[c0], bG1 = gb1[c0], bG2 = gb2[c0];

    // ---- prologue: pin this WG's G2/G4 weight fragments in LDS -----------
    // byte = g*65536 + ntl*32768 + kt*1024 + ln*16   (g: 0=aw2, 1=gw2)
    for (int idx = tid; idx < 8192; idx += NTH) {
        int g   = idx >> 12;
        int rem = idx & 4095;
        int ntl = rem >> 11;
        int kt  = (rem >> 6) & 31;
        int ln  = rem & 63;
        const unsigned short* src = (g ? p_g2 : p_a2)
            + ((size_t)((ng * 2 + ntl) * 32 + kt) * 64 + ln) * 8;
        *reinterpret_cast<s16x8*>(wlds + (size_t)idx * 16) =
            *reinterpret_cast<const s16x8*>(src);
    }
    __syncthreads();

    // wave's LDS weight bases (gemm, ntile, kq, lane folded in):
    const char* wlA2 = wlds + (size_t)wn * 32768 + (size_t)kq * 8192
                            + (size_t)lane * 16;
    const char* wlG2 = wlA2 + 65536;

    // kq-dependent offsets: 8 kt = 256 A elements; 8*512 B frag stride
    const size_t aq  = (size_t)kq * 256;
    const size_t bqx = (size_t)kq * 8 * 512;             // x half (kt 0..31)
    const size_t bqs = (size_t)(32 + kq * 8) * 512;      // state half (kt 32..63)

    float al_reg[4];                  // fp32 'aligned' tile (kq==0 waves)

    for (int t = 0; t < TT; ++t) {
        const unsigned short* xtb = xrowb + (size_t)t * HH;
        const unsigned rb = 4u * (unsigned)t;

        // ------- G1: h1 = gelu(concat(x_t, state) @ aw1 + ab1), K=2048 -----
        {
            f32x4 acc = kloop_x8(xtb + aq, a1f + bqx);   // x eighth BEFORE wait
            gbar_wait(gs, rb);                           // state ready (G4 t-1)
            acc = kloop_sc8(state + arow_off + aq, a1f + bqs, acc);  // 1 RT
            if (kq) red[wn][kq - 1][lane] = acc;
            __syncthreads();
            if (kq == 0) {
                acc += red[wn][0][lane] + red[wn][1][lane] + red[wn][2][lane];
#pragma unroll
                for (int j = 0; j < 4; ++j) {
                    float v = acc[j] + bA1;
                    sc_store_b16(h1 + (size_t)(mrow + q * 4 + j) * HH + c0,
                                 bf16b(gelu_exact(v)));
                }
            }
        }
        gbar_arrive(gs, ng, rb + 1);

        // ------- G2: aligned = h1 @ aw2 + ab2, K=1024 (B from LDS) ---------
        {
            gbar_wait(gs, rb + 1);
            f32x4 acc = kloop_ds8(h1 + arow_off + aq, wlA2);          // 1 RT
            if (kq) red[wn][kq - 1][lane] = acc;
            __syncthreads();
            if (kq == 0) {
                acc += red[wn][0][lane] + red[wn][1][lane] + red[wn][2][lane];
#pragma unroll
                for (int j = 0; j < 4; ++j) {
                    float v = acc[j] + bA2;
                    al_reg[j] = v;
                    sc_store_b16(albf + (size_t)(mrow + q * 4 + j) * HH + c0,
                                 bf16b(v));
                }
            }
        }
        gbar_arrive(gs, ng, rb + 2);

        // ------- G3: h2 = gelu(concat(x_t, aligned) @ gw1 + gb1), K=2048 ---
        {
            f32x4 acc = kloop_x8(xtb + aq, g1f + bqx);   // x eighth BEFORE wait
            gbar_wait(gs, rb + 2);                       // albf ready
            acc = kloop_sc8(albf + arow_off + aq, g1f + bqs, acc);    // 1 RT
            if (kq) red[wn][kq - 1][lane] = acc;
            __syncthreads();
            if (kq == 0) {
                acc += red[wn][0][lane] + red[wn][1][lane] + red[wn][2][lane];
#pragma unroll
                for (int j = 0; j < 4; ++j) {
                    float v = acc[j] + bG1;
                    sc_store_b16(h2 + (size_t)(mrow + q * 4 + j) * HH + c0,
                                 bf16b(gelu_exact(v)));
                }
            }
        }
        gbar_arrive(gs, ng, rb + 3);

        // ------- G4: gate = sigmoid(h2 @ gw2 + gb2); blend (B from LDS) ----
        {
            gbar_wait(gs, rb + 3);
            f32x4 acc = kloop_ds8(h2 + arow_off + aq, wlG2);          // 1 RT
            if (kq) red[wn][kq - 1][lane] = acc;
            __syncthreads();
            if (kq == 0) {
                acc += red[wn][0][lane] + red[wn][1][lane] + red[wn][2][lane];
#pragma unroll
                for (int j = 0; j < 4; ++j) {
                    int row = mrow + q * 4 + j;
                    size_t xo = (size_t)row * (TT * HH) + (size_t)t * HH + c0;
                    float gl = acc[j] + bG2;
                    float g  = 1.0f / (1.0f + expf(-gl));
                    float xv = X[xo];
                    float o  = g * al_reg[j] + (1.0f - g) * xv;
                    nt_store_f32(Out + xo, o);
                    sc_store_b16(state + (size_t)row * HH + c0, bf16b(o));
                }
            }
        }
        gbar_arrive(gs, ng, rb + 4);
    }
}

extern "C" void kernel_launch(void* const* d_in, const int* in_sizes, int n_in,
                              void* d_out, int out_size, void* d_ws, size_t ws_size,
                              hipStream_t stream) {
    (void)in_sizes; (void)n_in; (void)out_size; (void)ws_size;
    const float* X   = (const float*)d_in[0];
    const float* aw1 = (const float*)d_in[1];
    const float* ab1 = (const float*)d_in[2];
    const float* aw2 = (const float*)d_in[3];
    const float* ab2 = (const float*)d_in[4];
    const float* gw1 = (const float*)d_in[5];
    const float* gb1 = (const float*)d_in[6];
    const float* gw2 = (const float*)d_in[7];
    const float* gb2 = (const float*)d_in[8];
    float* Out = (float*)d_out;

    char* ws = (char*)d_ws;
    unsigned short* p_a1 = (unsigned short*)(ws);                 // 4 MB
    unsigned short* p_g1 = (unsigned short*)(ws + (4u  << 20));   // 4 MB
    unsigned short* p_a2 = (unsigned short*)(ws + (8u  << 20));   // 2 MB
    unsigned short* p_g2 = (unsigned short*)(ws + (10u << 20));   // 2 MB
    char* ctrl = ws + (12u << 20);
    unsigned* slots = (unsigned*)ctrl;                            // 8 grp x 64 u32
    unsigned short* state = (unsigned short*)(ctrl + 4096);       // 256 KB
    unsigned short* h1    = state + (size_t)BB * HH;              // 256 KB
    unsigned short* albf  = h1    + (size_t)BB * HH;              // 256 KB
    unsigned short* h2    = albf  + (size_t)BB * HH;              // 256 KB
    unsigned short* xbf   = (unsigned short*)(ws + (16u << 20));  // 128 MB

    pack_w_kernel<<<(64 * 64 * 64 + 255) / 256, 256, 0, stream>>>(aw1, p_a1, 2048, 1024);
    pack_w_kernel<<<(64 * 64 * 64 + 255) / 256, 256, 0, stream>>>(gw1, p_g1, 2048, 1024);
    pack_w_kernel<<<(64 * 32 * 64 + 255) / 256, 256, 0, stream>>>(aw2, p_a2, 1024, 1024);
    pack_w_kernel<<<(64 * 32 * 64 + 255) / 256, 256, 0, stream>>>(gw2, p_g2, 1024, 1024);
    {
        int n8 = BB * TT * HH / 8;
        pack_x_kernel<<<(n8 + 255) / 256, 256, 0, stream>>>(X, xbf, n8);
    }
    // Zero barrier slots + recurrent state every call (graph-replay safe).
    hipMemsetAsync(ctrl, 0, 4096 + (size_t)BB * HH * sizeof(unsigned short), stream);

    persist_kernel<<<NWG, NTH, 0, stream>>>(X, xbf, p_a1, ab1, p_a2, ab2,
                                            p_g1, gb1, p_g2, gb2,
                                            Out, state, h1, albf, h2, slots);
}

// Round 20
// 9284.644 us; speedup vs baseline: 3.0197x; 1.3657x over previous
//
#include <hip/hip_runtime.h>
#include <hip/hip_bf16.h>

// Problem constants
#define HH 1024
#define BB 128
#define TT 512
#define NWG 256      // 8 row-groups (mg = wg>>5, 16 rows) x 32 N-slices (ng = wg&31)
#define NTH 512      // 8 waves: 2 ntiles (wn = w>>2) x 4 K-quarters (kq = w&3)
#define NP 32

typedef float        f32x4 __attribute__((ext_vector_type(4)));
typedef short        s16x8 __attribute__((ext_vector_type(8)));

__device__ __forceinline__ unsigned short bf16b(float f) {
    union { __hip_bfloat16 h; unsigned short u; } cv;
    cv.h = __float2bfloat16(f);
    return cv.u;
}

__device__ __forceinline__ float gelu_exact(float x) {
    return 0.5f * x * (1.0f + erff(x * 0.70710678118654752440f));
}

// --- device-coherent (system-scope) accesses: cross-WG producer/consumer.
__device__ __forceinline__ void sc_load_b16x8(s16x8& v, const unsigned short* p) {
    asm volatile("global_load_dwordx4 %0, %1, off sc0 sc1" : "=v"(v) : "v"(p));
}
__device__ __forceinline__ void sc_load_u32(unsigned& v, const unsigned* p) {
    asm volatile("global_load_dword %0, %1, off sc0 sc1" : "=v"(v) : "v"(p));
}
__device__ __forceinline__ void sc_store_b16(unsigned short* p, unsigned int v) {
    asm volatile("global_store_short %0, %1, off sc0 sc1" :: "v"(p), "v"(v) : "memory");
}
__device__ __forceinline__ void sc_store_u32(unsigned* p, unsigned int v) {
    asm volatile("global_store_dword %0, %1, off sc0 sc1" :: "v"(p), "v"(v) : "memory");
}
// --- plain cached load (weights -> L2-resident under mod-8 mapping).
__device__ __forceinline__ void pl_load_b16x8(s16x8& v, const unsigned short* p) {
    asm volatile("global_load_dwordx4 %0, %1, off" : "=v"(v) : "v"(p));
}
// --- non-temporal store for streaming Out writes (no L2 pollution).
__device__ __forceinline__ void nt_store_f32(float* p, float v) {
    asm volatile("global_store_dword %0, %1, off nt" :: "v"(p), "v"(v) : "memory");
}
__device__ __forceinline__ void vm_wait0() {
    asm volatile("s_waitcnt vmcnt(0)" ::: "memory");
    __builtin_amdgcn_sched_barrier(0);   // rule #18
}

// ---------------------------------------------------------------------------
// Pack fp32 weight W[K][N] (row-major) into MFMA B-fragment layout, bf16.
// ---------------------------------------------------------------------------
__global__ __launch_bounds__(256) void pack_w_kernel(const float* __restrict__ W,
                                                     unsigned short* __restrict__ P,
                                                     int K, int N) {
    int tid = blockIdx.x * 256 + threadIdx.x;
    int KT = K >> 5;
    int total = (N >> 4) * KT * 64;
    if (tid >= total) return;
    int lane  = tid & 63;
    int ktile = (tid >> 6) % KT;
    int ntile = (tid >> 6) / KT;
    int k0 = ktile * 32 + (lane >> 4) * 8;
    int n  = ntile * 16 + (lane & 15);
    unsigned short tmp[8];
#pragma unroll
    for (int j = 0; j < 8; ++j)
        tmp[j] = bf16b(W[(size_t)(k0 + j) * N + n]);
    *reinterpret_cast<s16x8*>(P + (size_t)tid * 8) = *reinterpret_cast<const s16x8*>(tmp);
}

// ---------------------------------------------------------------------------
// Pack fp32 X into bf16 (identical rounding to the on-the-fly path).
// ---------------------------------------------------------------------------
__global__ __launch_bounds__(256) void pack_x_kernel(const float* __restrict__ X,
                                                     unsigned short* __restrict__ Xb,
                                                     int n8) {
    int i = blockIdx.x * 256 + threadIdx.x;
    if (i >= n8) return;
    f32x4 lo = *reinterpret_cast<const f32x4*>(X + (size_t)i * 8);
    f32x4 hi = *reinterpret_cast<const f32x4*>(X + (size_t)i * 8 + 4);
    unsigned short tmp[8];
#pragma unroll
    for (int j = 0; j < 4; ++j) {
        tmp[j]     = bf16b(lo[j]);
        tmp[j + 4] = bf16b(hi[j]);
    }
    *reinterpret_cast<s16x8*>(Xb + (size_t)i * 8) = *reinterpret_cast<const s16x8*>(tmp);
}

// ---------------------------------------------------------------------------
// Wf = aw2 @ gw1_state  (1024x1024, fp32 out). One 16x16 tile per 64-thr WG.
// A = aw2 rows (fp32 -> bf16), B = p_g1's packed state-half fragments
// (ktile 32..63 of the K=2048 packing).
// ---------------------------------------------------------------------------
__global__ __launch_bounds__(64) void wf_kernel(const float* __restrict__ aw2,
                                                const unsigned short* __restrict__ p_g1,
                                                float* __restrict__ Wf) {
    int bid = blockIdx.x;             // 64 x 64 tiles
    int tm = bid & 63, tn = bid >> 6;
    int lane = threadIdx.x;
    int r = lane & 15, q = lane >> 4;
    const float* arow = aw2 + (size_t)(tm * 16 + r) * 1024 + q * 8;
    const unsigned short* bfrag = p_g1 + ((size_t)(tn * 64 + 32) * 64 + lane) * 8;
    f32x4 acc = {};
    for (int kt = 0; kt < 32; ++kt) {
        f32x4 lo = *reinterpret_cast<const f32x4*>(arow + kt * 32);
        f32x4 hi = *reinterpret_cast<const f32x4*>(arow + kt * 32 + 4);
        s16x8 a;
#pragma unroll
        for (int j = 0; j < 4; ++j) {
            a[j]     = (short)bf16b(lo[j]);
            a[j + 4] = (short)bf16b(hi[j]);
        }
        s16x8 b = *reinterpret_cast<const s16x8*>(bfrag + (size_t)kt * 512);
        acc = __builtin_amdgcn_mfma_f32_16x16x32_bf16(a, b, acc, 0, 0, 0);
    }
#pragma unroll
    for (int i = 0; i < 4; ++i)
        Wf[(size_t)(tm * 16 + q * 4 + i) * 1024 + tn * 16 + r] = acc[i];
}

// bf = gb1 + ab2 @ gw1_state   (fp32, 1024 elems; exact fp32 math)
__global__ __launch_bounds__(256) void bf_kernel(const float* __restrict__ ab2,
                                                 const float* __restrict__ gw1,
                                                 const float* __restrict__ gb1,
                                                 float* __restrict__ bfv) {
    int n = blockIdx.x * 256 + threadIdx.x;   // grid 4
    float acc = gb1[n];
#pragma unroll 8
    for (int j = 0; j < 1024; ++j)
        acc += ab2[j] * gw1[(size_t)(1024 + j) * 1024 + n];
    bfv[n] = acc;
}

// ---------------------------------------------------------------------------
// Per-GROUP flag barrier (r16/r18-proven): 32 WGs of one row-group.
// ---------------------------------------------------------------------------
__device__ __forceinline__ void gbar_arrive(unsigned* gs, int ng, unsigned rnd) {
    asm volatile("s_waitcnt vmcnt(0)" ::: "memory");  // drain my sc/nt stores
    __syncthreads();                                   // all 8 waves drained
    if (threadIdx.x == 0)
        sc_store_u32(gs + ng, rnd);
}
__device__ __forceinline__ void gbar_wait(unsigned* gs, unsigned rnd) {
    if (threadIdx.x < 64) {
        const unsigned* p = gs + (threadIdx.x & 31);
        bool done;
        do {
            unsigned v;
            sc_load_u32(v, p);
            asm volatile("s_waitcnt vmcnt(0)" ::: "memory");
            done = __all(v >= rnd);
        } while (!done);
    }
    __syncthreads();
    __builtin_amdgcn_sched_barrier(0);
}

// x-eighth (8 kt) loop: plain cached loads, compiler-scheduled. Pre-wait.
__device__ __forceinline__ f32x4 kloop_x8(const unsigned short* xq,
                                          const unsigned short* bp) {
    f32x4 acc = {};
#pragma unroll
    for (int kt = 0; kt < 8; ++kt) {
        s16x8 a = *reinterpret_cast<const s16x8*>(xq + kt * 32);
        s16x8 b = *reinterpret_cast<const s16x8*>(bp + (size_t)kt * 512);
        acc = __builtin_amdgcn_mfma_f32_16x16x32_bf16(a, b, acc, 0, 0, 0);
    }
    return acc;
}

// 8-kt activation batch: 8 sc A + 8 plain B = 16 outstanding (PROVEN shape).
__device__ __forceinline__ f32x4 kloop_sc8(const unsigned short* Abase,
                                           const unsigned short* bp, f32x4 acc) {
    s16x8 a[8], b[8];
#pragma unroll
    for (int j = 0; j < 8; ++j)
        sc_load_b16x8(a[j], Abase + (size_t)j * 32);
#pragma unroll
    for (int j = 0; j < 8; ++j)
        pl_load_b16x8(b[j], bp + (size_t)j * 512);
    vm_wait0();
#pragma unroll
    for (int j = 0; j < 8; ++j)
        acc = __builtin_amdgcn_mfma_f32_16x16x32_bf16(a[j], b[j], acc, 0, 0, 0);
    return acc;
}

// P2 fused batch: 8 sc A (h1) + 8 plain aw2 B + 8 LDS Wf B. Same A feeds
// BOTH accumulators. 16 outstanding VMEM (proven shape).
__device__ __forceinline__ void kloop_p2(const unsigned short* Abase,
                                         const unsigned short* a2p,
                                         const char* wlWf,
                                         f32x4& accAl, f32x4& accH2) {
    s16x8 a[8], b[8];
#pragma unroll
    for (int j = 0; j < 8; ++j)
        sc_load_b16x8(a[j], Abase + (size_t)j * 32);
#pragma unroll
    for (int j = 0; j < 8; ++j)
        pl_load_b16x8(b[j], a2p + (size_t)j * 512);
    vm_wait0();
#pragma unroll
    for (int j = 0; j < 8; ++j) {
        accAl = __builtin_amdgcn_mfma_f32_16x16x32_bf16(a[j], b[j], accAl, 0, 0, 0);
        s16x8 bw = *reinterpret_cast<const s16x8*>(wlWf + (size_t)j * 1024);
        accH2 = __builtin_amdgcn_mfma_f32_16x16x32_bf16(a[j], bw, accH2, 0, 0, 0);
    }
}

// 8-kt batch vs LDS-pinned weights: 8 sc A (one drain), B from LDS.
__device__ __forceinline__ f32x4 kloop_ds8(const unsigned short* Abase,
                                           const char* wl) {
    f32x4 acc = {};
    s16x8 a[8];
#pragma unroll
    for (int j = 0; j < 8; ++j)
        sc_load_b16x8(a[j], Abase + (size_t)j * 32);
    vm_wait0();
#pragma unroll
    for (int j = 0; j < 8; ++j) {
        s16x8 b = *reinterpret_cast<const s16x8*>(wl + (size_t)j * 1024);
        acc = __builtin_amdgcn_mfma_f32_16x16x32_bf16(a[j], b, acc, 0, 0, 0);
    }
    return acc;
}

// ---------------------------------------------------------------------------
// Persistent kernel: 3 phases/step via Wf-fusion (aligned is linear in h1:
// aligned@gw1_s == h1@Wf + ab2@gw1_s with Wf = aw2@gw1_s precomputed).
//   P1: h1 = gelu(x@aw1_x + state@aw1_s + ab1)             [barrier]
//   P2: h2 = gelu(x@gw1_x + h1@Wf + bf); al = h1@aw2+ab2   [barrier]
//       (al kept in kq0 registers; albf buffer deleted)
//   P3: gate = sigmoid(h2@gw2 + gb2); out = g*al + (1-g)*x [barrier]
// 256 WGs = 8 row-groups x 32 col-slices; waves wn(2) x kq(4); all post-wait
// kloops are single 8sc+8plain batches (1 RT). LDS pins Wf+gw2 (128 KB);
// aw1/gw1/aw2 stream from L2 (mod-8 ng mapping). X bf16-prepacked; x-work
// and fp32 xv hoisted pre-wait. p_g1 passed EXPLICITLY (r19 bug fix).
// ---------------------------------------------------------------------------
__global__ __launch_bounds__(512, 1) void persist_kernel(
    const float* __restrict__ X, const unsigned short* __restrict__ Xb,
    const unsigned short* __restrict__ p_a1, const unsigned short* __restrict__ p_g1,
    const float* __restrict__ ab1,
    const unsigned short* __restrict__ p_a2, const float* __restrict__ ab2,
    const unsigned short* __restrict__ p_wf, const float* __restrict__ bfv,
    const unsigned short* __restrict__ p_g2, const float* __restrict__ gb2,
    float* __restrict__ Out,
    unsigned short* state, unsigned short* h1, unsigned short* h2,
    unsigned* slots)
{
    __shared__ __align__(16) char wlds[131072];   // 128 KB: Wf + gw2 frags
    __shared__ f32x4 redA[2][3][64];              // 6 KB: h2 / generic reduce
    __shared__ f32x4 redB[2][3][64];              // 6 KB: aligned reduce (P2)

    const int wg   = blockIdx.x;
    const int ng   = wg & (NP - 1);   // mod-8 XCD-friendly N-slice
    const int mg   = wg >> 5;         // row-group (16 rows)
    const int tid  = threadIdx.x;
    const int lane = tid & 63;
    const int w    = tid >> 6;        // 0..7
    const int wn   = w >> 2;          // 0..1 ntile
    const int kq   = w & 3;           // 0..3 K-quarter
    const int r    = lane & 15;
    const int q    = lane >> 4;

    const int mrow  = mg * 16;
    const int ncol  = ng * 32 + wn * 16;
    const int ntile = ncol >> 4;
    const int c0    = ncol + r;

    unsigned* gs = slots + mg * 64;

    const size_t arow_off = (size_t)(mrow + r) * HH + q * 8;
    const unsigned short* xrowb = Xb + (size_t)(mrow + r) * (TT * HH) + q * 8;

    const unsigned short* a1f = p_a1 + ((size_t)ntile * 64) * 512 + (size_t)lane * 8;
    const unsigned short* g1f = p_g1 + ((size_t)ntile * 64) * 512 + (size_t)lane * 8;
    const unsigned short* a2f = p_a2 + ((size_t)ntile * 32) * 512 + (size_t)lane * 8;

    const float bA1 = ab1[c0], bA2 = ab2[c0], bF = bfv[c0], bG2 = gb2[c0];

    // ---- prologue: pin Wf + gw2 fragments in LDS --------------------------
    // byte = g*65536 + ntl*32768 + kt*1024 + ln*16   (g: 0=Wf, 1=gw2)
    for (int idx = tid; idx < 8192; idx += NTH) {
        int g   = idx >> 12;
        int rem = idx & 4095;
        int ntl = rem >> 11;
        int kt  = (rem >> 6) & 31;
        int ln  = rem & 63;
        const unsigned short* src = (g ? p_g2 : p_wf)
            + ((size_t)((ng * 2 + ntl) * 32 + kt) * 64 + ln) * 8;
        *reinterpret_cast<s16x8*>(wlds + (size_t)idx * 16) =
            *reinterpret_cast<const s16x8*>(src);
    }
    __syncthreads();

    const char* wlWf = wlds + (size_t)wn * 32768 + (size_t)kq * 8192
                            + (size_t)lane * 16;
    const char* wlG2 = wlWf + 65536;

    // kq-dependent offsets
    const size_t aq  = (size_t)kq * 256;                 // 8 kt of A
    const size_t bqx = (size_t)kq * 8 * 512;             // x half (kt 0..31)
    const size_t bqs = (size_t)(32 + kq * 8) * 512;      // state half (kt 32..63)

    float al_reg[4];                  // fp32 'aligned' tile (kq==0 waves)
    f32x4 xacc;                       // carried x@aw1_x quarter

    // prologue: xacc = x(0)@aw1_x quarter
    xacc = kloop_x8(xrowb + aq, a1f + bqx);

    for (int t = 0; t < TT; ++t) {
        const unsigned short* xtb = xrowb + (size_t)t * HH;
        const unsigned rb = 3u * (unsigned)t;

        // ------- P1: h1 = gelu(x@aw1_x + state@aw1_s + ab1) ---------------
        {
            f32x4 acc = xacc;
            gbar_wait(gs, rb);                           // state ready
            acc = kloop_sc8(state + arow_off + aq, a1f + bqs, acc);   // 1 RT
            if (kq) redA[wn][kq - 1][lane] = acc;
            __syncthreads();
            if (kq == 0) {
                acc += redA[wn][0][lane] + redA[wn][1][lane] + redA[wn][2][lane];
#pragma unroll
                for (int j = 0; j < 4; ++j) {
                    float v = acc[j] + bA1;
                    sc_store_b16(h1 + (size_t)(mrow + q * 4 + j) * HH + c0,
                                 bf16b(gelu_exact(v)));
                }
            }
        }
        gbar_arrive(gs, ng, rb + 1);

        // ------- P2: h2 = gelu(x@gw1_x + h1@Wf + bf); al = h1@aw2 + ab2 ---
        {
            // pre-wait: x@gw1_x quarter (static input; EXPLICIT g1f base)
            f32x4 accH2 = kloop_x8(xtb + aq, g1f + bqx);
            gbar_wait(gs, rb + 1);                       // h1 ready
            f32x4 accAl = {};
            kloop_p2(h1 + arow_off + aq, a2f + bqx, wlWf, accAl, accH2); // 1 RT
            if (kq) { redA[wn][kq - 1][lane] = accH2; redB[wn][kq - 1][lane] = accAl; }
            __syncthreads();
            if (kq == 0) {
                accH2 += redA[wn][0][lane] + redA[wn][1][lane] + redA[wn][2][lane];
                accAl += redB[wn][0][lane] + redB[wn][1][lane] + redB[wn][2][lane];
#pragma unroll
                for (int j = 0; j < 4; ++j) {
                    al_reg[j] = accAl[j] + bA2;
                    sc_store_b16(h2 + (size_t)(mrow + q * 4 + j) * HH + c0,
                                 bf16b(gelu_exact(accH2[j] + bF)));
                }
            }
        }
        gbar_arrive(gs, ng, rb + 2);

        // ------- P3: gate = sigmoid(h2@gw2 + gb2); blend; next state ------
        {
            // pre-wait: next step's x@aw1_x quarter + this step's fp32 xv
            if (t + 1 < TT)
                xacc = kloop_x8(xtb + HH + aq, a1f + bqx);
            float xv[4];
            if (kq == 0) {
#pragma unroll
                for (int j = 0; j < 4; ++j)
                    xv[j] = X[(size_t)(mrow + q * 4 + j) * (TT * HH)
                              + (size_t)t * HH + c0];
            }
            gbar_wait(gs, rb + 2);                       // h2 ready
            f32x4 acc = kloop_ds8(h2 + arow_off + aq, wlG2);          // 1 RT
            if (kq) redA[wn][kq - 1][lane] = acc;
            __syncthreads();
            if (kq == 0) {
                acc += redA[wn][0][lane] + redA[wn][1][lane] + redA[wn][2][lane];
#pragma unroll
                for (int j = 0; j < 4; ++j) {
                    int row = mrow + q * 4 + j;
                    size_t xo = (size_t)row * (TT * HH) + (size_t)t * HH + c0;
                    float g = 1.0f / (1.0f + expf(-(acc[j] + bG2)));
                    float o = g * al_reg[j] + (1.0f - g) * xv[j];
                    nt_store_f32(Out + xo, o);
                    sc_store_b16(state + (size_t)row * HH + c0, bf16b(o));
                }
            }
        }
        gbar_arrive(gs, ng, rb + 3);
    }
}

extern "C" void kernel_launch(void* const* d_in, const int* in_sizes, int n_in,
                              void* d_out, int out_size, void* d_ws, size_t ws_size,
                              hipStream_t stream) {
    (void)in_sizes; (void)n_in; (void)out_size; (void)ws_size;
    const float* X   = (const float*)d_in[0];
    const float* aw1 = (const float*)d_in[1];
    const float* ab1 = (const float*)d_in[2];
    const float* aw2 = (const float*)d_in[3];
    const float* ab2 = (const float*)d_in[4];
    const float* gw1 = (const float*)d_in[5];
    const float* gb1 = (const float*)d_in[6];
    const float* gw2 = (const float*)d_in[7];
    const float* gb2 = (const float*)d_in[8];
    float* Out = (float*)d_out;

    char* ws = (char*)d_ws;
    unsigned short* p_a1 = (unsigned short*)(ws);                 // 4 MB
    unsigned short* p_g1 = (unsigned short*)(ws + (4u  << 20));   // 4 MB
    unsigned short* p_a2 = (unsigned short*)(ws + (8u  << 20));   // 2 MB
    unsigned short* p_g2 = (unsigned short*)(ws + (10u << 20));   // 2 MB
    unsigned short* p_wf = (unsigned short*)(ws + (12u << 20));   // 2 MB packed Wf
    char* ctrl = ws + (14u << 20);
    unsigned* slots = (unsigned*)ctrl;                            // 8 grp x 64 u32
    unsigned short* state = (unsigned short*)(ctrl + 4096);       // 256 KB
    unsigned short* h1    = state + (size_t)BB * HH;              // 256 KB
    unsigned short* h2    = h1    + (size_t)BB * HH;              // 256 KB
    float*          bfv   = (float*)(h2 + (size_t)BB * HH);       // 4 KB
    float*          Wft   = (float*)(ws + (15u << 20));           // 4 MB fp32 Wf
    unsigned short* xbf   = (unsigned short*)(ws + (20u << 20));  // 128 MB

    pack_w_kernel<<<(64 * 64 * 64 + 255) / 256, 256, 0, stream>>>(aw1, p_a1, 2048, 1024);
    pack_w_kernel<<<(64 * 64 * 64 + 255) / 256, 256, 0, stream>>>(gw1, p_g1, 2048, 1024);
    pack_w_kernel<<<(64 * 32 * 64 + 255) / 256, 256, 0, stream>>>(aw2, p_a2, 1024, 1024);
    pack_w_kernel<<<(64 * 32 * 64 + 255) / 256, 256, 0, stream>>>(gw2, p_g2, 1024, 1024);
    // Wf = aw2 @ gw1_state (uses packed p_g1), then pack; bf vector.
    wf_kernel<<<4096, 64, 0, stream>>>(aw2, p_g1, Wft);
    pack_w_kernel<<<(64 * 32 * 64 + 255) / 256, 256, 0, stream>>>(Wft, p_wf, 1024, 1024);
    bf_kernel<<<4, 256, 0, stream>>>(ab2, gw1, gb1, bfv);
    {
        int n8 = BB * TT * HH / 8;
        pack_x_kernel<<<(n8 + 255) / 256, 256, 0, stream>>>(X, xbf, n8);
    }
    // Zero barrier slots + recurrent state every call (graph-replay safe).
    hipMemsetAsync(ctrl, 0, 4096 + (size_t)BB * HH * sizeof(unsigned short), stream);

    persist_kernel<<<NWG, NTH, 0, stream>>>(X, xbf, p_a1, p_g1, ab1, p_a2, ab2,
                                            p_wf, bfv, p_g2, gb2,
                                            Out, state, h1, h2, slots);
}

// Round 21
// 8550.465 us; speedup vs baseline: 3.2790x; 1.0859x over previous
//
#include <hip/hip_runtime.h>
#include <hip/hip_bf16.h>

// Problem constants
#define HH 1024
#define BB 128
#define TT 512
#define NWG 256      // 8 row-groups (mg = wg>>5, 16 rows) x 32 N-slices (ng = wg&31)
#define NTH 512      // 8 waves: 2 ntiles (wn = w>>2) x 4 K-quarters (kq = w&3)
#define NP 32

typedef float        f32x4 __attribute__((ext_vector_type(4)));
typedef short        s16x8 __attribute__((ext_vector_type(8)));

__device__ __forceinline__ unsigned short bf16b(float f) {
    union { __hip_bfloat16 h; unsigned short u; } cv;
    cv.h = __float2bfloat16(f);
    return cv.u;
}

__device__ __forceinline__ float gelu_exact(float x) {
    return 0.5f * x * (1.0f + erff(x * 0.70710678118654752440f));
}

// --- device-coherent (system-scope) accesses: cross-WG producer/consumer.
__device__ __forceinline__ void sc_load_b16x8(s16x8& v, const unsigned short* p) {
    asm volatile("global_load_dwordx4 %0, %1, off sc0 sc1" : "=v"(v) : "v"(p));
}
__device__ __forceinline__ void sc_load_u32(unsigned& v, const unsigned* p) {
    asm volatile("global_load_dword %0, %1, off sc0 sc1" : "=v"(v) : "v"(p));
}
__device__ __forceinline__ void sc_store_b16(unsigned short* p, unsigned int v) {
    asm volatile("global_store_short %0, %1, off sc0 sc1" :: "v"(p), "v"(v) : "memory");
}
__device__ __forceinline__ void sc_store_u32(unsigned* p, unsigned int v) {
    asm volatile("global_store_dword %0, %1, off sc0 sc1" :: "v"(p), "v"(v) : "memory");
}
// --- plain cached load (weights -> L2-resident under mod-8 mapping).
__device__ __forceinline__ void pl_load_b16x8(s16x8& v, const unsigned short* p) {
    asm volatile("global_load_dwordx4 %0, %1, off" : "=v"(v) : "v"(p));
}
// --- non-temporal store for streaming Out writes (no L2 pollution).
__device__ __forceinline__ void nt_store_f32(float* p, float v) {
    asm volatile("global_store_dword %0, %1, off nt" :: "v"(p), "v"(v) : "memory");
}
__device__ __forceinline__ void vm_wait0() {
    asm volatile("s_waitcnt vmcnt(0)" ::: "memory");
    __builtin_amdgcn_sched_barrier(0);   // rule #18
}

// ---------------------------------------------------------------------------
// Pack fp32 weight W[K][N] (row-major) into MFMA B-fragment layout, bf16.
// ---------------------------------------------------------------------------
__global__ __launch_bounds__(256) void pack_w_kernel(const float* __restrict__ W,
                                                     unsigned short* __restrict__ P,
                                                     int K, int N) {
    int tid = blockIdx.x * 256 + threadIdx.x;
    int KT = K >> 5;
    int total = (N >> 4) * KT * 64;
    if (tid >= total) return;
    int lane  = tid & 63;
    int ktile = (tid >> 6) % KT;
    int ntile = (tid >> 6) / KT;
    int k0 = ktile * 32 + (lane >> 4) * 8;
    int n  = ntile * 16 + (lane & 15);
    unsigned short tmp[8];
#pragma unroll
    for (int j = 0; j < 8; ++j)
        tmp[j] = bf16b(W[(size_t)(k0 + j) * N + n]);
    *reinterpret_cast<s16x8*>(P + (size_t)tid * 8) = *reinterpret_cast<const s16x8*>(tmp);
}

// ---------------------------------------------------------------------------
// Pack fp32 X into bf16 (identical rounding to the on-the-fly path).
// ---------------------------------------------------------------------------
__global__ __launch_bounds__(256) void pack_x_kernel(const float* __restrict__ X,
                                                     unsigned short* __restrict__ Xb,
                                                     int n8) {
    int i = blockIdx.x * 256 + threadIdx.x;
    if (i >= n8) return;
    f32x4 lo = *reinterpret_cast<const f32x4*>(X + (size_t)i * 8);
    f32x4 hi = *reinterpret_cast<const f32x4*>(X + (size_t)i * 8 + 4);
    unsigned short tmp[8];
#pragma unroll
    for (int j = 0; j < 4; ++j) {
        tmp[j]     = bf16b(lo[j]);
        tmp[j + 4] = bf16b(hi[j]);
    }
    *reinterpret_cast<s16x8*>(Xb + (size_t)i * 8) = *reinterpret_cast<const s16x8*>(tmp);
}

// ---------------------------------------------------------------------------
// Wf = aw2 @ gw1_state  (1024x1024, fp32 out). One 16x16 tile per 64-thr WG.
// ---------------------------------------------------------------------------
__global__ __launch_bounds__(64) void wf_kernel(const float* __restrict__ aw2,
                                                const unsigned short* __restrict__ p_g1,
                                                float* __restrict__ Wf) {
    int bid = blockIdx.x;             // 64 x 64 tiles
    int tm = bid & 63, tn = bid >> 6;
    int lane = threadIdx.x;
    int r = lane & 15, q = lane >> 4;
    const float* arow = aw2 + (size_t)(tm * 16 + r) * 1024 + q * 8;
    const unsigned short* bfrag = p_g1 + ((size_t)(tn * 64 + 32) * 64 + lane) * 8;
    f32x4 acc = {};
    for (int kt = 0; kt < 32; ++kt) {
        f32x4 lo = *reinterpret_cast<const f32x4*>(arow + kt * 32);
        f32x4 hi = *reinterpret_cast<const f32x4*>(arow + kt * 32 + 4);
        s16x8 a;
#pragma unroll
        for (int j = 0; j < 4; ++j) {
            a[j]     = (short)bf16b(lo[j]);
            a[j + 4] = (short)bf16b(hi[j]);
        }
        s16x8 b = *reinterpret_cast<const s16x8*>(bfrag + (size_t)kt * 512);
        acc = __builtin_amdgcn_mfma_f32_16x16x32_bf16(a, b, acc, 0, 0, 0);
    }
#pragma unroll
    for (int i = 0; i < 4; ++i)
        Wf[(size_t)(tm * 16 + q * 4 + i) * 1024 + tn * 16 + r] = acc[i];
}

// bf = gb1 + ab2 @ gw1_state   (fp32, 1024 elems; exact fp32 math)
__global__ __launch_bounds__(256) void bf_kernel(const float* __restrict__ ab2,
                                                 const float* __restrict__ gw1,
                                                 const float* __restrict__ gb1,
                                                 float* __restrict__ bfv) {
    int n = blockIdx.x * 256 + threadIdx.x;   // grid 4
    float acc = gb1[n];
#pragma unroll 8
    for (int j = 0; j < 1024; ++j)
        acc += ab2[j] * gw1[(size_t)(1024 + j) * 1024 + n];
    bfv[n] = acc;
}

// ---------------------------------------------------------------------------
// Per-GROUP flag barrier (r16/r18/r20-proven): 32 WGs of one row-group.
// ---------------------------------------------------------------------------
__device__ __forceinline__ void gbar_arrive(unsigned* gs, int ng, unsigned rnd) {
    asm volatile("s_waitcnt vmcnt(0)" ::: "memory");  // drain my sc/nt stores
    __syncthreads();                                   // all 8 waves drained
    if (threadIdx.x == 0)
        sc_store_u32(gs + ng, rnd);
}
__device__ __forceinline__ void gbar_wait(unsigned* gs, unsigned rnd) {
    if (threadIdx.x < 64) {
        const unsigned* p = gs + (threadIdx.x & 31);
        bool done;
        do {
            unsigned v;
            sc_load_u32(v, p);
            asm volatile("s_waitcnt vmcnt(0)" ::: "memory");
            done = __all(v >= rnd);
        } while (!done);
    }
    __syncthreads();
    __builtin_amdgcn_sched_barrier(0);
}

// x-eighth (8 kt) loop: plain cached loads, compiler-scheduled. Pre-wait.
__device__ __forceinline__ f32x4 kloop_x8(const unsigned short* xq,
                                          const unsigned short* bp) {
    f32x4 acc = {};
#pragma unroll
    for (int kt = 0; kt < 8; ++kt) {
        s16x8 a = *reinterpret_cast<const s16x8*>(xq + kt * 32);
        s16x8 b = *reinterpret_cast<const s16x8*>(bp + (size_t)kt * 512);
        acc = __builtin_amdgcn_mfma_f32_16x16x32_bf16(a, b, acc, 0, 0, 0);
    }
    return acc;
}

// 8-kt activation batch: 8 sc A + 8 plain B = 16 outstanding (PROVEN shape).
__device__ __forceinline__ f32x4 kloop_sc8(const unsigned short* Abase,
                                           const unsigned short* bp, f32x4 acc) {
    s16x8 a[8], b[8];
#pragma unroll
    for (int j = 0; j < 8; ++j)
        sc_load_b16x8(a[j], Abase + (size_t)j * 32);
#pragma unroll
    for (int j = 0; j < 8; ++j)
        pl_load_b16x8(b[j], bp + (size_t)j * 512);
    vm_wait0();
#pragma unroll
    for (int j = 0; j < 8; ++j)
        acc = __builtin_amdgcn_mfma_f32_16x16x32_bf16(a[j], b[j], acc, 0, 0, 0);
    return acc;
}

// P2 fused batch: 8 sc A (h1) + 8 plain aw2 B + 8 LDS Wf B. Same A feeds
// BOTH accumulators. 16 outstanding VMEM (proven shape).
__device__ __forceinline__ void kloop_p2(const unsigned short* Abase,
                                         const unsigned short* a2p,
                                         const char* wlWf,
                                         f32x4& accAl, f32x4& accH2) {
    s16x8 a[8], b[8];
#pragma unroll
    for (int j = 0; j < 8; ++j)
        sc_load_b16x8(a[j], Abase + (size_t)j * 32);
#pragma unroll
    for (int j = 0; j < 8; ++j)
        pl_load_b16x8(b[j], a2p + (size_t)j * 512);
    vm_wait0();
#pragma unroll
    for (int j = 0; j < 8; ++j) {
        accAl = __builtin_amdgcn_mfma_f32_16x16x32_bf16(a[j], b[j], accAl, 0, 0, 0);
        s16x8 bw = *reinterpret_cast<const s16x8*>(wlWf + (size_t)j * 1024);
        accH2 = __builtin_amdgcn_mfma_f32_16x16x32_bf16(a[j], bw, accH2, 0, 0, 0);
    }
}

// 8-kt batch vs LDS-pinned weights: 8 sc A (one drain), B from LDS.
__device__ __forceinline__ f32x4 kloop_ds8(const unsigned short* Abase,
                                           const char* wl) {
    f32x4 acc = {};
    s16x8 a[8];
#pragma unroll
    for (int j = 0; j < 8; ++j)
        sc_load_b16x8(a[j], Abase + (size_t)j * 32);
    vm_wait0();
#pragma unroll
    for (int j = 0; j < 8; ++j) {
        s16x8 b = *reinterpret_cast<const s16x8*>(wl + (size_t)j * 1024);
        acc = __builtin_amdgcn_mfma_f32_16x16x32_bf16(a[j], b, acc, 0, 0, 0);
    }
    return acc;
}

// ---------------------------------------------------------------------------
// Persistent kernel (r20 skeleton + SYMMETRIC EPILOGUE SPREAD):
//   P1: h1 = gelu(x@aw1_x + state@aw1_s + ab1)             [barrier]
//   P2: h2 = gelu(x@gw1_x + h1@Wf + bf); al = h1@aw2+ab2   [barrier]
//   P3: gate = sigmoid(h2@gw2 + gb2); out = g*al + (1-g)*x [barrier]
// ALL 4 kq waves park partials in LDS; after the reduce-sync EVERY wave
// finalizes only its j==kq row-slice (1 gelu/sigmoid + 1 store per thread,
// was 4+8 on kq0 only) -> shorter critical path, symmetric arrival.
// Reduction order red[0]+red[1]+red[2]+red[3] is bit-identical to r20.
// al carried per-wave (1 fp32/thread). Everything else r20 verbatim.
// ---------------------------------------------------------------------------
__global__ __launch_bounds__(512, 1) void persist_kernel(
    const float* __restrict__ X, const unsigned short* __restrict__ Xb,
    const unsigned short* __restrict__ p_a1, const unsigned short* __restrict__ p_g1,
    const float* __restrict__ ab1,
    const unsigned short* __restrict__ p_a2, const float* __restrict__ ab2,
    const unsigned short* __restrict__ p_wf, const float* __restrict__ bfv,
    const unsigned short* __restrict__ p_g2, const float* __restrict__ gb2,
    float* __restrict__ Out,
    unsigned short* state, unsigned short* h1, unsigned short* h2,
    unsigned* slots)
{
    __shared__ __align__(16) char wlds[131072];   // 128 KB: Wf + gw2 frags
    __shared__ f32x4 redA[2][4][64];              // 8 KB: primary reduce
    __shared__ f32x4 redB[2][4][64];              // 8 KB: aligned reduce (P2)

    const int wg   = blockIdx.x;
    const int ng   = wg & (NP - 1);   // mod-8 XCD-friendly N-slice
    const int mg   = wg >> 5;         // row-group (16 rows)
    const int tid  = threadIdx.x;
    const int lane = tid & 63;
    const int w    = tid >> 6;        // 0..7
    const int wn   = w >> 2;          // 0..1 ntile
    const int kq   = w & 3;           // 0..3 K-quarter
    const int r    = lane & 15;
    const int q    = lane >> 4;

    const int mrow  = mg * 16;
    const int ncol  = ng * 32 + wn * 16;
    const int ntile = ncol >> 4;
    const int c0    = ncol + r;
    const int myrow = mrow + q * 4 + kq;    // this wave's epilogue row

    unsigned* gs = slots + mg * 64;

    const size_t arow_off = (size_t)(mrow + r) * HH + q * 8;
    const unsigned short* xrowb = Xb + (size_t)(mrow + r) * (TT * HH) + q * 8;

    const unsigned short* a1f = p_a1 + ((size_t)ntile * 64) * 512 + (size_t)lane * 8;
    const unsigned short* g1f = p_g1 + ((size_t)ntile * 64) * 512 + (size_t)lane * 8;
    const unsigned short* a2f = p_a2 + ((size_t)ntile * 32) * 512 + (size_t)lane * 8;

    const float bA1 = ab1[c0], bA2 = ab2[c0], bF = bfv[c0], bG2 = gb2[c0];

    // ---- prologue: pin Wf + gw2 fragments in LDS --------------------------
    for (int idx = tid; idx < 8192; idx += NTH) {
        int g   = idx >> 12;
        int rem = idx & 4095;
        int ntl = rem >> 11;
        int kt  = (rem >> 6) & 31;
        int ln  = rem & 63;
        const unsigned short* src = (g ? p_g2 : p_wf)
            + ((size_t)((ng * 2 + ntl) * 32 + kt) * 64 + ln) * 8;
        *reinterpret_cast<s16x8*>(wlds + (size_t)idx * 16) =
            *reinterpret_cast<const s16x8*>(src);
    }
    __syncthreads();

    const char* wlWf = wlds + (size_t)wn * 32768 + (size_t)kq * 8192
                            + (size_t)lane * 16;
    const char* wlG2 = wlWf + 65536;

    // kq-dependent offsets
    const size_t aq  = (size_t)kq * 256;                 // 8 kt of A
    const size_t bqx = (size_t)kq * 8 * 512;             // x half (kt 0..31)
    const size_t bqs = (size_t)(32 + kq * 8) * 512;      // state half (kt 32..63)

    float al_val = 0.f;               // fp32 'aligned' value for row myrow
    f32x4 xacc;                       // carried x@aw1_x quarter

    // prologue: xacc = x(0)@aw1_x quarter
    xacc = kloop_x8(xrowb + aq, a1f + bqx);

    for (int t = 0; t < TT; ++t) {
        const unsigned short* xtb = xrowb + (size_t)t * HH;
        const unsigned rb = 3u * (unsigned)t;

        // ------- P1: h1 = gelu(x@aw1_x + state@aw1_s + ab1) ---------------
        {
            f32x4 acc = xacc;
            gbar_wait(gs, rb);                           // state ready
            acc = kloop_sc8(state + arow_off + aq, a1f + bqs, acc);   // 1 RT
            redA[wn][kq][lane] = acc;
            __syncthreads();
            f32x4 s = redA[wn][0][lane] + redA[wn][1][lane]
                    + redA[wn][2][lane] + redA[wn][3][lane];
            float v = s[kq] + bA1;
            sc_store_b16(h1 + (size_t)myrow * HH + c0, bf16b(gelu_exact(v)));
        }
        gbar_arrive(gs, ng, rb + 1);

        // ------- P2: h2 = gelu(x@gw1_x + h1@Wf + bf); al = h1@aw2 + ab2 ---
        {
            // pre-wait: x@gw1_x quarter (static input)
            f32x4 accH2 = kloop_x8(xtb + aq, g1f + bqx);
            gbar_wait(gs, rb + 1);                       // h1 ready
            f32x4 accAl = {};
            kloop_p2(h1 + arow_off + aq, a2f + bqx, wlWf, accAl, accH2); // 1 RT
            redA[wn][kq][lane] = accH2;
            redB[wn][kq][lane] = accAl;
            __syncthreads();
            f32x4 sH = redA[wn][0][lane] + redA[wn][1][lane]
                     + redA[wn][2][lane] + redA[wn][3][lane];
            f32x4 sA = redB[wn][0][lane] + redB[wn][1][lane]
                     + redB[wn][2][lane] + redB[wn][3][lane];
            al_val = sA[kq] + bA2;
            sc_store_b16(h2 + (size_t)myrow * HH + c0,
                         bf16b(gelu_exact(sH[kq] + bF)));
        }
        gbar_arrive(gs, ng, rb + 2);

        // ------- P3: gate = sigmoid(h2@gw2 + gb2); blend; next state ------
        {
            // pre-wait: next step's x@aw1_x quarter + this step's fp32 xv
            if (t + 1 < TT)
                xacc = kloop_x8(xtb + HH + aq, a1f + bqx);
            float xv = X[(size_t)myrow * (TT * HH) + (size_t)t * HH + c0];
            gbar_wait(gs, rb + 2);                       // h2 ready
            f32x4 acc = kloop_ds8(h2 + arow_off + aq, wlG2);          // 1 RT
            redA[wn][kq][lane] = acc;
            __syncthreads();
            f32x4 s = redA[wn][0][lane] + redA[wn][1][lane]
                    + redA[wn][2][lane] + redA[wn][3][lane];
            float g = 1.0f / (1.0f + expf(-(s[kq] + bG2)));
            float o = g * al_val + (1.0f - g) * xv;
            nt_store_f32(Out + (size_t)myrow * (TT * HH) + (size_t)t * HH + c0, o);
            sc_store_b16(state + (size_t)myrow * HH + c0, bf16b(o));
        }
        gbar_arrive(gs, ng, rb + 3);
    }
}

extern "C" void kernel_launch(void* const* d_in, const int* in_sizes, int n_in,
                              void* d_out, int out_size, void* d_ws, size_t ws_size,
                              hipStream_t stream) {
    (void)in_sizes; (void)n_in; (void)out_size; (void)ws_size;
    const float* X   = (const float*)d_in[0];
    const float* aw1 = (const float*)d_in[1];
    const float* ab1 = (const float*)d_in[2];
    const float* aw2 = (const float*)d_in[3];
    const float* ab2 = (const float*)d_in[4];
    const float* gw1 = (const float*)d_in[5];
    const float* gb1 = (const float*)d_in[6];
    const float* gw2 = (const float*)d_in[7];
    const float* gb2 = (const float*)d_in[8];
    float* Out = (float*)d_out;

    char* ws = (char*)d_ws;
    unsigned short* p_a1 = (unsigned short*)(ws);                 // 4 MB
    unsigned short* p_g1 = (unsigned short*)(ws + (4u  << 20));   // 4 MB
    unsigned short* p_a2 = (unsigned short*)(ws + (8u  << 20));   // 2 MB
    unsigned short* p_g2 = (unsigned short*)(ws + (10u << 20));   // 2 MB
    unsigned short* p_wf = (unsigned short*)(ws + (12u << 20));   // 2 MB packed Wf
    char* ctrl = ws + (14u << 20);
    unsigned* slots = (unsigned*)ctrl;                            // 8 grp x 64 u32
    unsigned short* state = (unsigned short*)(ctrl + 4096);       // 256 KB
    unsigned short* h1    = state + (size_t)BB * HH;              // 256 KB
    unsigned short* h2    = h1    + (size_t)BB * HH;              // 256 KB
    float*          bfv   = (float*)(h2 + (size_t)BB * HH);       // 4 KB
    float*          Wft   = (float*)(ws + (15u << 20));           // 4 MB fp32 Wf
    unsigned short* xbf   = (unsigned short*)(ws + (20u << 20));  // 128 MB

    pack_w_kernel<<<(64 * 64 * 64 + 255) / 256, 256, 0, stream>>>(aw1, p_a1, 2048, 1024);
    pack_w_kernel<<<(64 * 64 * 64 + 255) / 256, 256, 0, stream>>>(gw1, p_g1, 2048, 1024);
    pack_w_kernel<<<(64 * 32 * 64 + 255) / 256, 256, 0, stream>>>(aw2, p_a2, 1024, 1024);
    pack_w_kernel<<<(64 * 32 * 64 + 255) / 256, 256, 0, stream>>>(gw2, p_g2, 1024, 1024);
    // Wf = aw2 @ gw1_state (uses packed p_g1), then pack; bf vector.
    wf_kernel<<<4096, 64, 0, stream>>>(aw2, p_g1, Wft);
    pack_w_kernel<<<(64 * 32 * 64 + 255) / 256, 256, 0, stream>>>(Wft, p_wf, 1024, 1024);
    bf_kernel<<<4, 256, 0, stream>>>(ab2, gw1, gb1, bfv);
    {
        int n8 = BB * TT * HH / 8;
        pack_x_kernel<<<(n8 + 255) / 256, 256, 0, stream>>>(X, xbf, n8);
    }
    // Zero barrier slots + recurrent state every call (graph-replay safe).
    hipMemsetAsync(ctrl, 0, 4096 + (size_t)BB * HH * sizeof(unsigned short), stream);

    persist_kernel<<<NWG, NTH, 0, stream>>>(X, xbf, p_a1, p_g1, ab1, p_a2, ab2,
                                            p_wf, bfv, p_g2, gb2,
                                            Out, state, h1, h2, slots);
}